// Round 6
// baseline (452.791 us; speedup 1.0000x reference)
//
#include <hip/hip_runtime.h>

typedef unsigned int u32;
typedef _Float16 h2v __attribute__((ext_vector_type(2)));
typedef _Float16 h8v __attribute__((ext_vector_type(8)));
typedef float f4v __attribute__((ext_vector_type(4)));

namespace {

constexpr int kB = 256, kT = 1024, kS = 96, kStart = 1;
constexpr float kCF = 3.5f;
constexpr float kLn2 = 0.69314718055994531f;
constexpr int kNT = 16;                    // batch tiles of 16
constexpr int kSlotU = 832;                // u32 per (bt,t) slot: 768 EF + 64 mask
constexpr int kNSlots = kNT * kT;          // 16384
constexpr size_t kEFGu = (size_t)kNSlots * kSlotU;
// f32-unit offsets into ws after the EF table
constexpr size_t OPF  = kEFGu;
constexpr size_t OWB  = OPF + (size_t)kB * kS;
constexpr size_t OLF  = OWB + (size_t)kB * kS;
constexpr size_t OLB  = OLF + kB;
constexpr size_t ONUM = OLB + kB;
constexpr size_t OMS  = ONUM + kB;
constexpr size_t kNeedBytes = (OMS + kB) * 4;

__device__ __forceinline__ u32 pkmul(u32 a, u32 b) {
  u32 d; asm("v_pk_mul_f16 %0, %1, %2" : "=v"(d) : "v"(a), "v"(b)); return d;
}
__device__ __forceinline__ u32 pkmax(u32 a, u32 b) {
  u32 d; asm("v_pk_max_f16 %0, %1, %2" : "=v"(d) : "v"(a), "v"(b)); return d;
}
__device__ __forceinline__ u32 pkrtz(float a, float b) {
  return __builtin_bit_cast(u32, __builtin_amdgcn_cvt_pkrtz(a, b));
}

// per-tile renorm: exact power-of-2 scale toward max-exponent 11 (fp16)
__device__ __forceinline__ void renorm(u32 (&B)[6][2], float& Lacc) {
  u32 m = B[0][0];
#pragma unroll
  for (int kt = 0; kt < 6; ++kt)
#pragma unroll
    for (int pr = 0; pr < 2; ++pr)
      if (kt | pr) m = pkmax(m, B[kt][pr]);
  m = pkmax(m, (u32)__shfl_xor((int)m, 16, 64));
  m = pkmax(m, (u32)__shfl_xor((int)m, 32, 64));
  m = pkmax(m, (m >> 16) | (m << 16));
  int e = (int)((m >> 10) & 31);
  e = e < 1 ? 1 : (e > 25 ? 25 : e);
  u32 sb = (u32)(26 - e) << 10;  // fp16 2^(11-e), exact
  sb |= sb << 16;
#pragma unroll
  for (int kt = 0; kt < 6; ++kt)
#pragma unroll
    for (int pr = 0; pr < 2; ++pr) B[kt][pr] = pkmul(B[kt][pr], sb);
  Lacc += (float)(e - 11) * kLn2;
}

// ---------------- prep: EF table (fp16, MFMA C-fragment order) + numerator ----------------
__global__ __launch_bounds__(256) void crf_prep(
    const float* __restrict__ F, const int* __restrict__ states,
    const float* __restrict__ mask, const float* __restrict__ trans,
    u32* __restrict__ efg, float* __restrict__ ws) {
  __shared__ float red[256];
  const int blk = blockIdx.x;
  const int tid = threadIdx.x;
  if (blk < kNSlots) {
    const int bt = blk >> 10, t = blk & 1023;
    u32* out = efg + (size_t)blk * kSlotU;
#pragma unroll
    for (int qq = 0; qq < 4; ++qq) {
      const int c = qq * 256 + tid;
      if (c < 768) {
        const int ll = c / 12, j = c % 12;
        const int col = ll & 15, q4 = (ll >> 4) * 4;
        const int s0 = (j >> 1) * 16 + q4 + (j & 1) * 2;
        const int b = bt * 16 + col;
        const float2 fv = *(const float2*)(F + ((size_t)b * kT + t) * kS + s0);
        out[c] = pkrtz(__expf(fv.x - kCF), __expf(fv.y - kCF));
      } else if (c < kSlotU) {
        const int col = (c - 768) & 15;
        out[c] = (mask[(size_t)(bt * 16 + col) * kT + t] > 0.f) ? ~0u : 0u;
      }
    }
    return;
  }
  // numerator + mask-count
  const int b = blk - kNSlots;
  const int* st = states + b * kT;
  const float* Fb = F + (size_t)b * kT * kS;
  const float* mb = mask + b * kT;
  float acc = 0.f, msum = 0.f;
  for (int t = tid; t < kT; t += 256) {
    const int cu = st[t];
    const int pr = (t > 0) ? st[t - 1] : kStart;
    const float mk = mb[t];
    acc += (Fb[(size_t)t * kS + cu] + trans[cu * kS + pr]) * mk;
    msum += mk;
  }
  red[tid] = acc;
  __syncthreads();
  if (tid < 128) red[tid] += red[tid + 128];
  __syncthreads();
  if (tid < 64) {
    float v = red[tid] + red[tid + 64];
#pragma unroll
    for (int off = 32; off > 0; off >>= 1) v += __shfl_xor(v, off, 64);
    if (tid == 0) ws[ONUM + b] = v;
  }
  __syncthreads();
  red[tid] = msum;
  __syncthreads();
  if (tid < 128) red[tid] += red[tid + 128];
  __syncthreads();
  if (tid < 64) {
    float v = red[tid] + red[tid + 64];
#pragma unroll
    for (int off = 32; off > 0; off >>= 1) v += __shfl_xor(v, off, 64);
    if (tid == 0) ws[OMS + b] = v;
  }
}

// ---------------- dual chains: 1 wave per batch-tile, fwd+bwd interleaved ----------------
// No LDS, no barriers. K=32 MFMA; the C/D->B layout mismatch is absorbed into
// A's column permutation (pi): B-slot (m, q=l>>4, j) holds position
// p = 32m + 16*(jj>>1) + 4q + 2*(jj&1) + (j&1), jj=j>>1 -- exactly the C-layout
// register regrouping (Bf[2m][0],Bf[2m][1],Bf[2m+1][0],Bf[2m+1][1]).

#define LOADSLOT(EA, MV, T) do {                                              \
    const u32* sp_ = tbase + (size_t)(T) * kSlotU + l * 12;                   \
    EA[0] = ((const uint4*)sp_)[0];                                           \
    EA[1] = ((const uint4*)sp_)[1];                                           \
    EA[2] = ((const uint4*)sp_)[2];                                           \
    MV = tbase[(size_t)(T) * kSlotU + 768 + l];                               \
  } while (0)

#define CSTEP(EF, MF, EB, MB, S, RENF) do {                                   \
    const u32 efF[12] = {EF[0].x, EF[0].y, EF[0].z, EF[0].w,                  \
                         EF[1].x, EF[1].y, EF[1].z, EF[1].w,                  \
                         EF[2].x, EF[2].y, EF[2].z, EF[2].w};                 \
    const u32 efB[12] = {EB[0].x, EB[0].y, EB[0].z, EB[0].w,                  \
                         EB[1].x, EB[1].y, EB[1].z, EB[1].w,                  \
                         EB[2].x, EB[2].y, EB[2].z, EB[2].w};                 \
    const u32 mwF = MF, mwB = MB;                                             \
    if ((S) + 2 < 512) {                                                      \
      LOADSLOT(EF, MF, (S) + 2);                                              \
      LOADSLOT(EB, MB, 1023 - ((S) + 2));                                     \
    }                                                                         \
    u32 BuB[6][2];                                                            \
    _Pragma("unroll") for (int kt = 0; kt < 6; ++kt)                          \
      _Pragma("unroll") for (int pr = 0; pr < 2; ++pr)                        \
        BuB[kt][pr] = pkmul(Bb[kt][pr], efB[kt * 2 + pr]);                    \
    h8v bkF[3], bkB[3];                                                       \
    _Pragma("unroll") for (int m = 0; m < 3; ++m) {                           \
      uint4 tf{Bf[2 * m][0], Bf[2 * m][1], Bf[2 * m + 1][0], Bf[2 * m + 1][1]}; \
      uint4 tb{BuB[2 * m][0], BuB[2 * m][1], BuB[2 * m + 1][0], BuB[2 * m + 1][1]}; \
      bkF[m] = __builtin_bit_cast(h8v, tf);                                   \
      bkB[m] = __builtin_bit_cast(h8v, tb);                                   \
    }                                                                         \
    f4v Cf[6], Cb[6];                                                         \
    _Pragma("unroll") for (int it = 0; it < 6; ++it) {                        \
      Cf[it] = __builtin_amdgcn_mfma_f32_16x16x32_f16(Af[it][0], bkF[0], z4, 0, 0, 0); \
      Cb[it] = __builtin_amdgcn_mfma_f32_16x16x32_f16(Ab[it][0], bkB[0], z4, 0, 0, 0); \
    }                                                                         \
    _Pragma("unroll") for (int m = 1; m < 3; ++m)                             \
      _Pragma("unroll") for (int it = 0; it < 6; ++it) {                      \
        Cf[it] = __builtin_amdgcn_mfma_f32_16x16x32_f16(Af[it][m], bkF[m], Cf[it], 0, 0, 0); \
        Cb[it] = __builtin_amdgcn_mfma_f32_16x16x32_f16(Ab[it][m], bkB[m], Cb[it], 0, 0, 0); \
      }                                                                       \
    _Pragma("unroll") for (int it = 0; it < 6; ++it)                          \
      _Pragma("unroll") for (int pr = 0; pr < 2; ++pr) {                      \
        u32 cF = pkmul(pkrtz(Cf[it][2 * pr], Cf[it][2 * pr + 1]), efF[it * 2 + pr]); \
        Bf[it][pr] = mwF ? cF : Bf[it][pr];                                   \
        u32 cB = pkrtz(Cb[it][2 * pr], Cb[it][2 * pr + 1]);                   \
        Bb[it][pr] = mwB ? cB : Bb[it][pr];                                   \
      }                                                                       \
    if (RENF) renorm(Bf, LF); else renorm(Bb, LB);                            \
  } while (0)

__global__ __launch_bounds__(64, 1) void crf_chains2(
    const u32* __restrict__ efg, const float* __restrict__ trans,
    float* __restrict__ ws) {
  const int bt = blockIdx.x;
  const int l = threadIdx.x;
  const int q_ = l >> 4, r = l & 15;
  const u32* tbase = efg + (size_t)bt * kT * kSlotU;

  // A matrices in fragment layout with the pi column-permutation baked in.
  h8v Af[6][3], Ab[6][3];
#pragma unroll
  for (int it = 0; it < 6; ++it)
#pragma unroll
    for (int m = 0; m < 3; ++m) {
      u32 wf[4], wb[4];
#pragma unroll
      for (int jj = 0; jj < 4; ++jj) {
        const int p0 = 32 * m + 16 * (jj >> 1) + 4 * q_ + 2 * (jj & 1);
        const int rowi = 16 * it + r;
        wf[jj] = pkrtz(__expf(trans[rowi * kS + p0] - kCF),
                       __expf(trans[rowi * kS + p0 + 1] - kCF));
        wb[jj] = pkrtz(__expf(trans[p0 * kS + rowi] - kCF),
                       __expf(trans[(p0 + 1) * kS + rowi] - kCF));
      }
      uint4 uf{wf[0], wf[1], wf[2], wf[3]}, ub{wb[0], wb[1], wb[2], wb[3]};
      Af[it][m] = __builtin_bit_cast(h8v, uf);
      Ab[it][m] = __builtin_bit_cast(h8v, ub);
    }

  u32 Bf[6][2], Bb[6][2];
#pragma unroll
  for (int kt = 0; kt < 6; ++kt)
#pragma unroll
    for (int pr = 0; pr < 2; ++pr) {
      Bf[kt][pr] = 0u;
      Bb[kt][pr] = 0x3C003C00u;   // ones
    }
  if (q_ == 0) Bf[0][0] = 0x3C000000u;   // p0 = e_{state 1} (high half of pair {0,1})

  float LF = 0.f, LB = 0.f;
  const f4v z4 = {0.f, 0.f, 0.f, 0.f};

  uint4 eF0[3], eF1[3], eB0[3], eB1[3];
  u32 mF0, mF1, mB0, mB1;
  LOADSLOT(eF0, mF0, 0);
  LOADSLOT(eF1, mF1, 1);
  LOADSLOT(eB0, mB0, 1023);
  LOADSLOT(eB1, mB1, 1022);

  for (int s = 0; s < 512; s += 2) {
    CSTEP(eF0, mF0, eB0, mB0, s, true);
    CSTEP(eF1, mF1, eB1, mB1, s + 1, false);
  }

  float* dstF = ws + OPF + ((size_t)bt * 16 + r) * kS;
  float* dstB = ws + OWB + ((size_t)bt * 16 + r) * kS;
#pragma unroll
  for (int kt = 0; kt < 6; ++kt)
#pragma unroll
    for (int pr = 0; pr < 2; ++pr) {
      const int s0 = kt * 16 + q_ * 4 + pr * 2;
      const h2v hf = __builtin_bit_cast(h2v, Bf[kt][pr]);
      const h2v hb = __builtin_bit_cast(h2v, Bb[kt][pr]);
      dstF[s0] = (float)hf[0];
      dstF[s0 + 1] = (float)hf[1];
      dstB[s0] = (float)hb[0];
      dstB[s0 + 1] = (float)hb[1];
    }
  if (l < 16) {
    ws[OLF + bt * 16 + l] = LF;
    ws[OLB + bt * 16 + l] = LB;
  }
}

// ---------------- finalize ----------------
__global__ __launch_bounds__(64) void crf_fin(
    const float* __restrict__ ws, float* __restrict__ out) {
  const int b = blockIdx.x, l = threadIdx.x;
  float d = ws[OPF + (size_t)b * kS + l] * ws[OWB + (size_t)b * kS + l];
  if (l < 32) d += ws[OPF + (size_t)b * kS + 64 + l] * ws[OWB + (size_t)b * kS + 64 + l];
#pragma unroll
  for (int off = 32; off; off >>= 1) d += __shfl_xor(d, off, 64);
  if (l == 0)
    out[b] = (ws[OLF + b] + ws[OLB + b] + logf(d) + 2.f * kCF * ws[OMS + b]) - ws[ONUM + b];
}

// ================= fallback path (R3, known-good) if ws is too small =================
constexpr int FB_PF = 0;
constexpr int FB_LF = kB * kS;
constexpr int FB_WB = FB_LF + kB;
constexpr int FB_LB = FB_WB + kB * kS;

__device__ __forceinline__ void renorm96(const float4* pv, float& pnew, float& Lacc) {
  float4 m4 = pv[0];
#pragma unroll
  for (int k = 1; k < 12; ++k) {
    m4.x = fmaxf(m4.x, pv[k].x); m4.y = fmaxf(m4.y, pv[k].y);
    m4.z = fmaxf(m4.z, pv[k].z); m4.w = fmaxf(m4.w, pv[k].w);
  }
  float m = fmaxf(fmaxf(m4.x, m4.y), fmaxf(m4.z, m4.w));
  m = fmaxf(m, __shfl_xor(m, 1, 64));
  const int e = (__float_as_int(m) >> 23) & 0xFF;
  const float scale = __int_as_float((254 - e) << 23);
  Lacc += (float)(e - 127) * kLn2;
  pnew *= scale;
}

__global__ __launch_bounds__(192) void fb_halves(
    const float* __restrict__ F, const float* __restrict__ mask,
    const float* __restrict__ trans, float* __restrict__ ws) {
  const bool bwd = blockIdx.x >= kB;
  const int b = bwd ? (blockIdx.x - kB) : blockIdx.x;
  const int tid = threadIdx.x;
  const int h = tid & 1;
  const int i = tid >> 1;
  __shared__ __align__(16) float pbuf[2][kS];
  __shared__ __align__(16) float fl[2][16 * kS];
  __shared__ __align__(16) float ml[kT];
  const float* Fb = F + (size_t)b * kT * kS;
  float mwv[48];
  if (!bwd) {
    const float4* tp = (const float4*)(trans + i * kS + h * 48);
#pragma unroll
    for (int k = 0; k < 12; ++k) {
      const float4 tv = tp[k];
      mwv[4 * k + 0] = __expf(tv.x - kCF); mwv[4 * k + 1] = __expf(tv.y - kCF);
      mwv[4 * k + 2] = __expf(tv.z - kCF); mwv[4 * k + 3] = __expf(tv.w - kCF);
    }
  } else {
#pragma unroll
    for (int k = 0; k < 48; ++k) mwv[k] = __expf(trans[(h * 48 + k) * kS + i] - kCF);
  }
  const int gb0 = bwd ? (kT - 16) : 0;
  const int gstep = bwd ? -16 : 16;
  {
    const float4* s = (const float4*)(Fb + (size_t)gb0 * kS + tid * 8);
    const float4 a = s[0], c4 = s[1];
    *(float4*)&fl[0][tid * 8] = a;
    *(float4*)&fl[0][tid * 8 + 4] = c4;
    const float4* mb4 = (const float4*)(mask + (size_t)b * kT);
    for (int idx = tid; idx < kT / 4; idx += 192) ((float4*)ml)[idx] = mb4[idx];
    if (!bwd && h == 0) pbuf[0][i] = (i == kStart) ? 1.0f : 0.0f;
  }
  __syncthreads();
  float Lacc = 0.0f;
  float pown = bwd ? 1.0f : ((i == kStart) ? 1.0f : 0.0f);
  int cur = 0;
  float4 pfa, pfb;
  for (int tc = 0; tc < 32; ++tc) {
    const int fbuf = tc & 1;
    if (tc < 31) {
      const float4* s = (const float4*)(Fb + (size_t)(gb0 + (tc + 1) * gstep) * kS + tid * 8);
      pfa = s[0]; pfb = s[1];
    }
#pragma unroll
    for (int tt = 0; tt < 16; ++tt) {
      const int tl = tc * 16 + tt;
      const int t = bwd ? (kT - 1 - tl) : tl;
      const float f = fl[fbuf][(bwd ? (15 - tt) : tt) * kS + i];
      const float mkv = ml[t];
      if (!bwd) {
        const float* pc = &pbuf[cur][h * 48];
        float4 pv[12];
#pragma unroll
        for (int k = 0; k < 12; ++k) pv[k] = ((const float4*)pc)[k];
        float a0 = 0.f, a1 = 0.f, a2 = 0.f, a3 = 0.f;
#pragma unroll
        for (int k = 0; k < 12; ++k) {
          a0 = fmaf(mwv[4 * k + 0], pv[k].x, a0); a1 = fmaf(mwv[4 * k + 1], pv[k].y, a1);
          a2 = fmaf(mwv[4 * k + 2], pv[k].z, a2); a3 = fmaf(mwv[4 * k + 3], pv[k].w, a3);
        }
        float acc = (a0 + a1) + (a2 + a3);
        acc += __shfl_xor(acc, 1, 64);
        float pnew = (mkv > 0.f) ? acc * __expf(f - kCF) : pown;
        if (((tt + 1) & 7) == 0) renorm96(pv, pnew, Lacc);
        if (tt == 15 && tc < 31) {
          *(float4*)&fl[fbuf ^ 1][tid * 8] = pfa;
          *(float4*)&fl[fbuf ^ 1][tid * 8 + 4] = pfb;
        }
        if (h == 0) pbuf[cur ^ 1][i] = pnew;
        __syncthreads();
        pown = pnew;
      } else {
        const float uu = pown * __expf(f - kCF);
        if (h == 0) pbuf[cur ^ 1][i] = uu;
        if (tt == 15 && tc < 31) {
          *(float4*)&fl[fbuf ^ 1][tid * 8] = pfa;
          *(float4*)&fl[fbuf ^ 1][tid * 8 + 4] = pfb;
        }
        __syncthreads();
        const float* pc = &pbuf[cur ^ 1][h * 48];
        float4 pv[12];
#pragma unroll
        for (int k = 0; k < 12; ++k) pv[k] = ((const float4*)pc)[k];
        float a0 = 0.f, a1 = 0.f, a2 = 0.f, a3 = 0.f;
#pragma unroll
        for (int k = 0; k < 12; ++k) {
          a0 = fmaf(mwv[4 * k + 0], pv[k].x, a0); a1 = fmaf(mwv[4 * k + 1], pv[k].y, a1);
          a2 = fmaf(mwv[4 * k + 2], pv[k].z, a2); a3 = fmaf(mwv[4 * k + 3], pv[k].w, a3);
        }
        float acc = (a0 + a1) + (a2 + a3);
        acc += __shfl_xor(acc, 1, 64);
        float pnew = (mkv > 0.f) ? acc : pown;
        if (((tt + 1) & 7) == 0) renorm96(pv, pnew, Lacc);
        pown = pnew;
      }
      cur ^= 1;
    }
  }
  if (h == 0) ws[(bwd ? FB_WB : FB_PF) + b * kS + i] = pown;
  if (tid == 0) ws[(bwd ? FB_LB : FB_LF) + b] = Lacc;
}

__global__ __launch_bounds__(256) void fb_finalize(
    const float* __restrict__ F, const int* __restrict__ states,
    const float* __restrict__ mask, const float* __restrict__ trans,
    const float* __restrict__ ws, float* __restrict__ out) {
  const int b = blockIdx.x;
  const int tid = threadIdx.x;
  const int* st = states + b * kT;
  const float* Fb = F + (size_t)b * kT * kS;
  const float* mb = mask + b * kT;
  float acc = 0.f;
  for (int t = tid; t < kT; t += 256) {
    const int cu = st[t];
    const int pr = (t > 0) ? st[t - 1] : kStart;
    acc += (Fb[(size_t)t * kS + cu] + trans[cu * kS + pr]) * mb[t];
  }
  __shared__ float red[256];
  red[tid] = acc;
  __syncthreads();
  if (tid < 128) red[tid] += red[tid + 128];
  __syncthreads();
  float numv = 0.f;
  if (tid < 64) {
    float v = red[tid] + red[tid + 64];
#pragma unroll
    for (int off = 32; off > 0; off >>= 1) v += __shfl_xor(v, off, 64);
    numv = v;
  }
  __syncthreads();
  float dv = 0.f;
  if (tid < kS) dv = ws[FB_PF + b * kS + tid] * ws[FB_WB + b * kS + tid];
  red[tid] = dv;
  __syncthreads();
  if (tid < 128) red[tid] += red[tid + 128];
  __syncthreads();
  if (tid < 64) {
    float v = red[tid] + red[tid + 64];
#pragma unroll
    for (int off = 32; off > 0; off >>= 1) v += __shfl_xor(v, off, 64);
    if (tid == 0) out[b] = (ws[FB_LF + b] + ws[FB_LB + b] + logf(v)) - numv;
  }
}

}  // namespace

extern "C" void kernel_launch(void* const* d_in, const int* in_sizes, int n_in,
                              void* d_out, int out_size, void* d_ws, size_t ws_size,
                              hipStream_t stream) {
  const float* F      = (const float*)d_in[0];
  const int*   states = (const int*)d_in[1];
  const float* mask   = (const float*)d_in[2];
  const float* trans  = (const float*)d_in[3];
  float* out = (float*)d_out;
  if (ws_size >= kNeedBytes) {
    hipLaunchKernelGGL(crf_prep, dim3(kNSlots + kB), dim3(256), 0, stream,
                       F, states, mask, trans, (u32*)d_ws, (float*)d_ws);
    hipLaunchKernelGGL(crf_chains2, dim3(kNT), dim3(64), 0, stream,
                       (const u32*)d_ws, trans, (float*)d_ws);
    hipLaunchKernelGGL(crf_fin, dim3(kB), dim3(64), 0, stream,
                       (const float*)d_ws, out);
  } else {
    float* ws = (float*)d_ws;
    hipLaunchKernelGGL(fb_halves, dim3(2 * kB), dim3(192), 0, stream, F, mask, trans, ws);
    hipLaunchKernelGGL(fb_finalize, dim3(kB), dim3(256), 0, stream,
                       F, states, mask, trans, ws, out);
  }
}

// Round 7
// 365.124 us; speedup vs baseline: 1.2401x; 1.2401x over previous
//
#include <hip/hip_runtime.h>

typedef unsigned int u32;
typedef _Float16 h2v __attribute__((ext_vector_type(2)));
typedef _Float16 h8v __attribute__((ext_vector_type(8)));
typedef float f4v __attribute__((ext_vector_type(4)));

namespace {

constexpr int kB = 256, kT = 1024, kS = 96, kStart = 1;
constexpr float kCF = 3.5f;
constexpr float kLn2 = 0.69314718055994531f;
constexpr int kNT = 16;                    // batch tiles of 16
constexpr int kSlotU = 832;                // u32 per (bt,t) slot: 768 EF + 64 mask
constexpr int kNSlots = kNT * kT;          // 16384
constexpr size_t kEFGu = (size_t)kNSlots * kSlotU;
// f32-unit offsets into ws after the EF table
constexpr size_t OPF  = kEFGu;
constexpr size_t OWB  = OPF + (size_t)kB * kS;
constexpr size_t OLF  = OWB + (size_t)kB * kS;
constexpr size_t OLB  = OLF + kB;
constexpr size_t ONUM = OLB + kB;
constexpr size_t OMS  = ONUM + kB;
constexpr size_t kNeedBytes = (OMS + kB) * 4;

__device__ __forceinline__ u32 pkmul(u32 a, u32 b) {
  u32 d; asm("v_pk_mul_f16 %0, %1, %2" : "=v"(d) : "v"(a), "v"(b)); return d;
}
__device__ __forceinline__ u32 pkmax(u32 a, u32 b) {
  u32 d; asm("v_pk_max_f16 %0, %1, %2" : "=v"(d) : "v"(a), "v"(b)); return d;
}
__device__ __forceinline__ u32 pkrtz(float a, float b) {
  return __builtin_bit_cast(u32, __builtin_amdgcn_cvt_pkrtz(a, b));
}

// ---------------- prep: EF table (fp16, MFMA C-fragment order) + numerator ----------------
__global__ __launch_bounds__(256) void crf_prep(
    const float* __restrict__ F, const int* __restrict__ states,
    const float* __restrict__ mask, const float* __restrict__ trans,
    u32* __restrict__ efg, float* __restrict__ ws) {
  __shared__ float red[256];
  const int blk = blockIdx.x;
  const int tid = threadIdx.x;
  if (blk < kNSlots) {
    const int bt = blk >> 10, t = blk & 1023;
    u32* out = efg + (size_t)blk * kSlotU;
#pragma unroll
    for (int qq = 0; qq < 4; ++qq) {
      const int c = qq * 256 + tid;
      if (c < 768) {
        const int ll = c / 12, j = c % 12;
        const int col = ll & 15, q4 = (ll >> 4) * 4;
        const int s0 = (j >> 1) * 16 + q4 + (j & 1) * 2;
        const int b = bt * 16 + col;
        const float2 fv = *(const float2*)(F + ((size_t)b * kT + t) * kS + s0);
        out[c] = pkrtz(__expf(fv.x - kCF), __expf(fv.y - kCF));
      } else if (c < kSlotU) {
        const int col = (c - 768) & 15;
        out[c] = (mask[(size_t)(bt * 16 + col) * kT + t] > 0.f) ? ~0u : 0u;
      }
    }
    return;
  }
  // numerator + mask-count
  const int b = blk - kNSlots;
  const int* st = states + b * kT;
  const float* Fb = F + (size_t)b * kT * kS;
  const float* mb = mask + b * kT;
  float acc = 0.f, msum = 0.f;
  for (int t = tid; t < kT; t += 256) {
    const int cu = st[t];
    const int pr = (t > 0) ? st[t - 1] : kStart;
    const float mk = mb[t];
    acc += (Fb[(size_t)t * kS + cu] + trans[cu * kS + pr]) * mk;
    msum += mk;
  }
  red[tid] = acc;
  __syncthreads();
  if (tid < 128) red[tid] += red[tid + 128];
  __syncthreads();
  if (tid < 64) {
    float v = red[tid] + red[tid + 64];
#pragma unroll
    for (int off = 32; off > 0; off >>= 1) v += __shfl_xor(v, off, 64);
    if (tid == 0) ws[ONUM + b] = v;
  }
  __syncthreads();
  red[tid] = msum;
  __syncthreads();
  if (tid < 128) red[tid] += red[tid + 128];
  __syncthreads();
  if (tid < 64) {
    float v = red[tid] + red[tid + 64];
#pragma unroll
    for (int off = 32; off > 0; off >>= 1) v += __shfl_xor(v, off, 64);
    if (tid == 0) ws[OMS + b] = v;
  }
}

// ---------------- dual chains: 1 wave per batch-tile, fwd+bwd interleaved ----------------
// No LDS, no barriers. K=32 MFMA with the pi column-permutation baked into A
// (verified R6, absmax=0). New in R7: stale lag-1 per-column renorm (off the
// critical path) + depth-4 register prefetch ring.

#define LOADSLOT(EA, MV, T) do {                                              \
    const u32* sp_ = tbase + (size_t)(T) * kSlotU + l * 12;                   \
    EA[0] = ((const uint4*)sp_)[0];                                           \
    EA[1] = ((const uint4*)sp_)[1];                                           \
    EA[2] = ((const uint4*)sp_)[2];                                           \
    MV = tbase[(size_t)(T) * kSlotU + 768 + l];                               \
  } while (0)

// per-column stale max -> exact power-of-2 scale (fp16 pair), bookkeeping in LX.
// Column max: reg tree (this lane's col slice) + q-reduction (xor16, xor32) +
// half-swap. All lanes of a column agree; scale/L are per-column.
#define STALEMAX(BX, LX) ({                                                   \
    u32 m_ = BX[0][0];                                                        \
    _Pragma("unroll") for (int kt_ = 0; kt_ < 6; ++kt_)                       \
      _Pragma("unroll") for (int pr_ = 0; pr_ < 2; ++pr_)                     \
        if (kt_ | pr_) m_ = pkmax(m_, BX[kt_][pr_]);                          \
    m_ = pkmax(m_, (u32)__shfl_xor((int)m_, 16, 64));                         \
    m_ = pkmax(m_, (u32)__shfl_xor((int)m_, 32, 64));                         \
    m_ = pkmax(m_, (m_ >> 16) | (m_ << 16));                                  \
    int e_ = (int)((m_ >> 10) & 31);                                          \
    e_ = e_ < 1 ? 1 : (e_ > 29 ? 29 : e_);                                    \
    LX += (float)(e_ - 15) * kLn2;                                            \
    u32 s_ = (u32)(30 - e_) << 10;                                            \
    s_ | (s_ << 16);                                                          \
  })

#define CSTEP(K, S, RENF) do {                                                \
    const u32 efF[12] = {eF[K][0].x, eF[K][0].y, eF[K][0].z, eF[K][0].w,      \
                         eF[K][1].x, eF[K][1].y, eF[K][1].z, eF[K][1].w,      \
                         eF[K][2].x, eF[K][2].y, eF[K][2].z, eF[K][2].w};     \
    const u32 efB[12] = {eB[K][0].x, eB[K][0].y, eB[K][0].z, eB[K][0].w,      \
                         eB[K][1].x, eB[K][1].y, eB[K][1].z, eB[K][1].w,      \
                         eB[K][2].x, eB[K][2].y, eB[K][2].z, eB[K][2].w};     \
    const u32 mwF = mFv[K], mwB = mBv[K];                                     \
    { int tF_ = (S) + 4; if (tF_ > 511) tF_ = 511;                            \
      int tB_ = 1023 - ((S) + 4); if (tB_ < 512) tB_ = 512;                   \
      LOADSLOT(eF[K], mFv[K], tF_);                                          \
      LOADSLOT(eB[K], mBv[K], tB_); }                                        \
    u32 sc_;                                                                  \
    if (RENF) sc_ = STALEMAX(Bf, LF); else sc_ = STALEMAX(Bb, LB);            \
    u32 BuB[6][2];                                                            \
    _Pragma("unroll") for (int kt = 0; kt < 6; ++kt)                          \
      _Pragma("unroll") for (int pr = 0; pr < 2; ++pr)                        \
        BuB[kt][pr] = pkmul(Bb[kt][pr], efB[kt * 2 + pr]);                    \
    h8v bkF[3], bkB[3];                                                       \
    _Pragma("unroll") for (int m = 0; m < 3; ++m) {                           \
      uint4 tf{Bf[2 * m][0], Bf[2 * m][1], Bf[2 * m + 1][0], Bf[2 * m + 1][1]}; \
      uint4 tb{BuB[2 * m][0], BuB[2 * m][1], BuB[2 * m + 1][0], BuB[2 * m + 1][1]}; \
      bkF[m] = __builtin_bit_cast(h8v, tf);                                   \
      bkB[m] = __builtin_bit_cast(h8v, tb);                                   \
    }                                                                         \
    f4v Cf[6], Cb[6];                                                         \
    _Pragma("unroll") for (int it = 0; it < 6; ++it) {                        \
      Cf[it] = __builtin_amdgcn_mfma_f32_16x16x32_f16(Af[it][0], bkF[0], z4, 0, 0, 0); \
      Cb[it] = __builtin_amdgcn_mfma_f32_16x16x32_f16(Ab[it][0], bkB[0], z4, 0, 0, 0); \
    }                                                                         \
    _Pragma("unroll") for (int m = 1; m < 3; ++m)                             \
      _Pragma("unroll") for (int it = 0; it < 6; ++it) {                      \
        Cf[it] = __builtin_amdgcn_mfma_f32_16x16x32_f16(Af[it][m], bkF[m], Cf[it], 0, 0, 0); \
        Cb[it] = __builtin_amdgcn_mfma_f32_16x16x32_f16(Ab[it][m], bkB[m], Cb[it], 0, 0, 0); \
      }                                                                       \
    _Pragma("unroll") for (int it = 0; it < 6; ++it)                          \
      _Pragma("unroll") for (int pr = 0; pr < 2; ++pr) {                      \
        u32 cF = pkmul(pkrtz(Cf[it][2 * pr], Cf[it][2 * pr + 1]), efF[it * 2 + pr]); \
        cF = mwF ? cF : Bf[it][pr];                                           \
        if (RENF) cF = pkmul(cF, sc_);                                        \
        Bf[it][pr] = cF;                                                      \
        u32 cB = pkrtz(Cb[it][2 * pr], Cb[it][2 * pr + 1]);                   \
        cB = mwB ? cB : Bb[it][pr];                                           \
        if (!(RENF)) cB = pkmul(cB, sc_);                                     \
        Bb[it][pr] = cB;                                                      \
      }                                                                       \
  } while (0)

__global__ __launch_bounds__(64, 1) void crf_chains2(
    const u32* __restrict__ efg, const float* __restrict__ trans,
    float* __restrict__ ws) {
  const int bt = blockIdx.x;
  const int l = threadIdx.x;
  const int q_ = l >> 4, r = l & 15;
  const u32* tbase = efg + (size_t)bt * kT * kSlotU;

  // A matrices in fragment layout with the pi column-permutation baked in.
  h8v Af[6][3], Ab[6][3];
#pragma unroll
  for (int it = 0; it < 6; ++it)
#pragma unroll
    for (int m = 0; m < 3; ++m) {
      u32 wf[4], wb[4];
#pragma unroll
      for (int jj = 0; jj < 4; ++jj) {
        const int p0 = 32 * m + 16 * (jj >> 1) + 4 * q_ + 2 * (jj & 1);
        const int rowi = 16 * it + r;
        wf[jj] = pkrtz(__expf(trans[rowi * kS + p0] - kCF),
                       __expf(trans[rowi * kS + p0 + 1] - kCF));
        wb[jj] = pkrtz(__expf(trans[p0 * kS + rowi] - kCF),
                       __expf(trans[(p0 + 1) * kS + rowi] - kCF));
      }
      uint4 uf{wf[0], wf[1], wf[2], wf[3]}, ub{wb[0], wb[1], wb[2], wb[3]};
      Af[it][m] = __builtin_bit_cast(h8v, uf);
      Ab[it][m] = __builtin_bit_cast(h8v, ub);
    }

  u32 Bf[6][2], Bb[6][2];
#pragma unroll
  for (int kt = 0; kt < 6; ++kt)
#pragma unroll
    for (int pr = 0; pr < 2; ++pr) {
      Bf[kt][pr] = 0u;
      Bb[kt][pr] = 0x3C003C00u;   // ones
    }
  if (q_ == 0) Bf[0][0] = 0x3C000000u;   // p0 = e_{state 1}

  float LF = 0.f, LB = 0.f;
  const f4v z4 = {0.f, 0.f, 0.f, 0.f};

  uint4 eF[4][3], eB[4][3];
  u32 mFv[4], mBv[4];
  LOADSLOT(eF[0], mFv[0], 0);
  LOADSLOT(eB[0], mBv[0], 1023);
  LOADSLOT(eF[1], mFv[1], 1);
  LOADSLOT(eB[1], mBv[1], 1022);
  LOADSLOT(eF[2], mFv[2], 2);
  LOADSLOT(eB[2], mBv[2], 1021);
  LOADSLOT(eF[3], mFv[3], 3);
  LOADSLOT(eB[3], mBv[3], 1020);

  for (int s = 0; s < 512; s += 4) {
    CSTEP(0, s, true);
    CSTEP(1, s + 1, false);
    CSTEP(2, s + 2, true);
    CSTEP(3, s + 3, false);
  }

  float* dstF = ws + OPF + ((size_t)bt * 16 + r) * kS;
  float* dstB = ws + OWB + ((size_t)bt * 16 + r) * kS;
#pragma unroll
  for (int kt = 0; kt < 6; ++kt)
#pragma unroll
    for (int pr = 0; pr < 2; ++pr) {
      const int s0 = kt * 16 + q_ * 4 + pr * 2;
      const h2v hf = __builtin_bit_cast(h2v, Bf[kt][pr]);
      const h2v hb = __builtin_bit_cast(h2v, Bb[kt][pr]);
      dstF[s0] = (float)hf[0];
      dstF[s0 + 1] = (float)hf[1];
      dstB[s0] = (float)hb[0];
      dstB[s0 + 1] = (float)hb[1];
    }
  if (l < 16) {
    ws[OLF + bt * 16 + l] = LF;
    ws[OLB + bt * 16 + l] = LB;
  }
}

// ---------------- finalize ----------------
__global__ __launch_bounds__(64) void crf_fin(
    const float* __restrict__ ws, float* __restrict__ out) {
  const int b = blockIdx.x, l = threadIdx.x;
  float d = ws[OPF + (size_t)b * kS + l] * ws[OWB + (size_t)b * kS + l];
  if (l < 32) d += ws[OPF + (size_t)b * kS + 64 + l] * ws[OWB + (size_t)b * kS + 64 + l];
#pragma unroll
  for (int off = 32; off; off >>= 1) d += __shfl_xor(d, off, 64);
  if (l == 0)
    out[b] = (ws[OLF + b] + ws[OLB + b] + logf(d) + 2.f * kCF * ws[OMS + b]) - ws[ONUM + b];
}

// ================= fallback path (R3, known-good) if ws is too small =================
constexpr int FB_PF = 0;
constexpr int FB_LF = kB * kS;
constexpr int FB_WB = FB_LF + kB;
constexpr int FB_LB = FB_WB + kB * kS;

__device__ __forceinline__ void renorm96(const float4* pv, float& pnew, float& Lacc) {
  float4 m4 = pv[0];
#pragma unroll
  for (int k = 1; k < 12; ++k) {
    m4.x = fmaxf(m4.x, pv[k].x); m4.y = fmaxf(m4.y, pv[k].y);
    m4.z = fmaxf(m4.z, pv[k].z); m4.w = fmaxf(m4.w, pv[k].w);
  }
  float m = fmaxf(fmaxf(m4.x, m4.y), fmaxf(m4.z, m4.w));
  m = fmaxf(m, __shfl_xor(m, 1, 64));
  const int e = (__float_as_int(m) >> 23) & 0xFF;
  const float scale = __int_as_float((254 - e) << 23);
  Lacc += (float)(e - 127) * kLn2;
  pnew *= scale;
}

__global__ __launch_bounds__(192) void fb_halves(
    const float* __restrict__ F, const float* __restrict__ mask,
    const float* __restrict__ trans, float* __restrict__ ws) {
  const bool bwd = blockIdx.x >= kB;
  const int b = bwd ? (blockIdx.x - kB) : blockIdx.x;
  const int tid = threadIdx.x;
  const int h = tid & 1;
  const int i = tid >> 1;
  __shared__ __align__(16) float pbuf[2][kS];
  __shared__ __align__(16) float fl[2][16 * kS];
  __shared__ __align__(16) float ml[kT];
  const float* Fb = F + (size_t)b * kT * kS;
  float mwv[48];
  if (!bwd) {
    const float4* tp = (const float4*)(trans + i * kS + h * 48);
#pragma unroll
    for (int k = 0; k < 12; ++k) {
      const float4 tv = tp[k];
      mwv[4 * k + 0] = __expf(tv.x - kCF); mwv[4 * k + 1] = __expf(tv.y - kCF);
      mwv[4 * k + 2] = __expf(tv.z - kCF); mwv[4 * k + 3] = __expf(tv.w - kCF);
    }
  } else {
#pragma unroll
    for (int k = 0; k < 48; ++k) mwv[k] = __expf(trans[(h * 48 + k) * kS + i] - kCF);
  }
  const int gb0 = bwd ? (kT - 16) : 0;
  const int gstep = bwd ? -16 : 16;
  {
    const float4* s = (const float4*)(Fb + (size_t)gb0 * kS + tid * 8);
    const float4 a = s[0], c4 = s[1];
    *(float4*)&fl[0][tid * 8] = a;
    *(float4*)&fl[0][tid * 8 + 4] = c4;
    const float4* mb4 = (const float4*)(mask + (size_t)b * kT);
    for (int idx = tid; idx < kT / 4; idx += 192) ((float4*)ml)[idx] = mb4[idx];
    if (!bwd && h == 0) pbuf[0][i] = (i == kStart) ? 1.0f : 0.0f;
  }
  __syncthreads();
  float Lacc = 0.0f;
  float pown = bwd ? 1.0f : ((i == kStart) ? 1.0f : 0.0f);
  int cur = 0;
  float4 pfa, pfb;
  for (int tc = 0; tc < 32; ++tc) {
    const int fbuf = tc & 1;
    if (tc < 31) {
      const float4* s = (const float4*)(Fb + (size_t)(gb0 + (tc + 1) * gstep) * kS + tid * 8);
      pfa = s[0]; pfb = s[1];
    }
#pragma unroll
    for (int tt = 0; tt < 16; ++tt) {
      const int tl = tc * 16 + tt;
      const int t = bwd ? (kT - 1 - tl) : tl;
      const float f = fl[fbuf][(bwd ? (15 - tt) : tt) * kS + i];
      const float mkv = ml[t];
      if (!bwd) {
        const float* pc = &pbuf[cur][h * 48];
        float4 pv[12];
#pragma unroll
        for (int k = 0; k < 12; ++k) pv[k] = ((const float4*)pc)[k];
        float a0 = 0.f, a1 = 0.f, a2 = 0.f, a3 = 0.f;
#pragma unroll
        for (int k = 0; k < 12; ++k) {
          a0 = fmaf(mwv[4 * k + 0], pv[k].x, a0); a1 = fmaf(mwv[4 * k + 1], pv[k].y, a1);
          a2 = fmaf(mwv[4 * k + 2], pv[k].z, a2); a3 = fmaf(mwv[4 * k + 3], pv[k].w, a3);
        }
        float acc = (a0 + a1) + (a2 + a3);
        acc += __shfl_xor(acc, 1, 64);
        float pnew = (mkv > 0.f) ? acc * __expf(f - kCF) : pown;
        if (((tt + 1) & 7) == 0) renorm96(pv, pnew, Lacc);
        if (tt == 15 && tc < 31) {
          *(float4*)&fl[fbuf ^ 1][tid * 8] = pfa;
          *(float4*)&fl[fbuf ^ 1][tid * 8 + 4] = pfb;
        }
        if (h == 0) pbuf[cur ^ 1][i] = pnew;
        __syncthreads();
        pown = pnew;
      } else {
        const float uu = pown * __expf(f - kCF);
        if (h == 0) pbuf[cur ^ 1][i] = uu;
        if (tt == 15 && tc < 31) {
          *(float4*)&fl[fbuf ^ 1][tid * 8] = pfa;
          *(float4*)&fl[fbuf ^ 1][tid * 8 + 4] = pfb;
        }
        __syncthreads();
        const float* pc = &pbuf[cur ^ 1][h * 48];
        float4 pv[12];
#pragma unroll
        for (int k = 0; k < 12; ++k) pv[k] = ((const float4*)pc)[k];
        float a0 = 0.f, a1 = 0.f, a2 = 0.f, a3 = 0.f;
#pragma unroll
        for (int k = 0; k < 12; ++k) {
          a0 = fmaf(mwv[4 * k + 0], pv[k].x, a0); a1 = fmaf(mwv[4 * k + 1], pv[k].y, a1);
          a2 = fmaf(mwv[4 * k + 2], pv[k].z, a2); a3 = fmaf(mwv[4 * k + 3], pv[k].w, a3);
        }
        float acc = (a0 + a1) + (a2 + a3);
        acc += __shfl_xor(acc, 1, 64);
        float pnew = (mkv > 0.f) ? acc : pown;
        if (((tt + 1) & 7) == 0) renorm96(pv, pnew, Lacc);
        pown = pnew;
      }
      cur ^= 1;
    }
  }
  if (h == 0) ws[(bwd ? FB_WB : FB_PF) + b * kS + i] = pown;
  if (tid == 0) ws[(bwd ? FB_LB : FB_LF) + b] = Lacc;
}

__global__ __launch_bounds__(256) void fb_finalize(
    const float* __restrict__ F, const int* __restrict__ states,
    const float* __restrict__ mask, const float* __restrict__ trans,
    const float* __restrict__ ws, float* __restrict__ out) {
  const int b = blockIdx.x;
  const int tid = threadIdx.x;
  const int* st = states + b * kT;
  const float* Fb = F + (size_t)b * kT * kS;
  const float* mb = mask + b * kT;
  float acc = 0.f;
  for (int t = tid; t < kT; t += 256) {
    const int cu = st[t];
    const int pr = (t > 0) ? st[t - 1] : kStart;
    acc += (Fb[(size_t)t * kS + cu] + trans[cu * kS + pr]) * mb[t];
  }
  __shared__ float red[256];
  red[tid] = acc;
  __syncthreads();
  if (tid < 128) red[tid] += red[tid + 128];
  __syncthreads();
  float numv = 0.f;
  if (tid < 64) {
    float v = red[tid] + red[tid + 64];
#pragma unroll
    for (int off = 32; off > 0; off >>= 1) v += __shfl_xor(v, off, 64);
    numv = v;
  }
  __syncthreads();
  float dv = 0.f;
  if (tid < kS) dv = ws[FB_PF + b * kS + tid] * ws[FB_WB + b * kS + tid];
  red[tid] = dv;
  __syncthreads();
  if (tid < 128) red[tid] += red[tid + 128];
  __syncthreads();
  if (tid < 64) {
    float v = red[tid] + red[tid + 64];
#pragma unroll
    for (int off = 32; off > 0; off >>= 1) v += __shfl_xor(v, off, 64);
    if (tid == 0) out[b] = (ws[FB_LF + b] + ws[FB_LB + b] + logf(v)) - numv;
  }
}

}  // namespace

extern "C" void kernel_launch(void* const* d_in, const int* in_sizes, int n_in,
                              void* d_out, int out_size, void* d_ws, size_t ws_size,
                              hipStream_t stream) {
  const float* F      = (const float*)d_in[0];
  const int*   states = (const int*)d_in[1];
  const float* mask   = (const float*)d_in[2];
  const float* trans  = (const float*)d_in[3];
  float* out = (float*)d_out;
  if (ws_size >= kNeedBytes) {
    hipLaunchKernelGGL(crf_prep, dim3(kNSlots + kB), dim3(256), 0, stream,
                       F, states, mask, trans, (u32*)d_ws, (float*)d_ws);
    hipLaunchKernelGGL(crf_chains2, dim3(kNT), dim3(64), 0, stream,
                       (const u32*)d_ws, trans, (float*)d_ws);
    hipLaunchKernelGGL(crf_fin, dim3(kB), dim3(64), 0, stream,
                       (const float*)d_ws, out);
  } else {
    float* ws = (float*)d_ws;
    hipLaunchKernelGGL(fb_halves, dim3(2 * kB), dim3(192), 0, stream, F, mask, trans, ws);
    hipLaunchKernelGGL(fb_finalize, dim3(kB), dim3(256), 0, stream,
                       F, states, mask, trans, ws, out);
  }
}